// Round 1
// baseline (2690.360 us; speedup 1.0000x reference)
//
#include <hip/hip_runtime.h>

#define NN 50000
#define NE 800000

// ---------------- CSR build ----------------
__global__ __launch_bounds__(256) void count_deg_kernel(const int* __restrict__ dst,
                                                        int* __restrict__ deg, int n) {
    int e = blockIdx.x * 256 + threadIdx.x;
    if (e < n) atomicAdd(&deg[dst[e]], 1);
}

__global__ __launch_bounds__(1024) void scan_kernel(const int* __restrict__ deg,
                                                    int* __restrict__ off, int n) {
    __shared__ int s[1024];
    int t = threadIdx.x;
    int chunk = (n + 1023) >> 10;
    int lo = t * chunk; if (lo > n) lo = n;
    int hi = lo + chunk; if (hi > n) hi = n;
    int sum = 0;
    for (int i = lo; i < hi; ++i) sum += deg[i];
    s[t] = sum;
    __syncthreads();
    for (int d = 1; d < 1024; d <<= 1) {
        int v = (t >= d) ? s[t - d] : 0;
        __syncthreads();
        s[t] += v;
        __syncthreads();
    }
    int base = (t == 0) ? 0 : s[t - 1];
    for (int i = lo; i < hi; ++i) { off[i] = base; base += deg[i]; }
    if (t == 1023) off[n] = s[1023];
}

__global__ __launch_bounds__(256) void init_cursor_kernel(const int* __restrict__ off,
                                                          int* __restrict__ cursor, int n) {
    int i = blockIdx.x * 256 + threadIdx.x;
    if (i < n) cursor[i] = off[i];
}

__global__ __launch_bounds__(256) void fill_kernel(const int* __restrict__ src,
                                                   const int* __restrict__ dst,
                                                   int* __restrict__ cursor,
                                                   int* __restrict__ col, int n) {
    int e = blockIdx.x * 256 + threadIdx.x;
    if (e < n) {
        int p = atomicAdd(&cursor[dst[e]], 1);
        col[p] = src[e];
    }
}

// ---------------- weight transpose ----------------
__global__ __launch_bounds__(256) void transpose_kernel(const float* __restrict__ W,
                                                        float* __restrict__ WT, int R, int C) {
    int i = blockIdx.x * 256 + threadIdx.x;
    if (i < R * C) {
        int r = i / C, c = i % C;
        WT[c * R + r] = W[i];
    }
}

// ---------------- SAGE: mean-aggregate + lin_l  ----------------
// one thread per node; neighbor rows pulled via CSR; mean row kept in VGPRs;
// WlT read at wave-uniform addresses (scalar loads).
template <int FIN, int FOUT>
__global__ __launch_bounds__(64, 2) void agg_mean_mm_kernel(
    const float* __restrict__ h, const int* __restrict__ off, const int* __restrict__ col,
    const float* __restrict__ WlT, float* __restrict__ tmp, int n) {
    int i = blockIdx.x * 64 + threadIdx.x;
    if (i >= n) return;
    float acc[FIN];
#pragma unroll
    for (int k = 0; k < FIN; ++k) acc[k] = 0.f;
    int p0 = off[i], p1 = off[i + 1];
    for (int p = p0; p < p1; ++p) {
        const float4* r = (const float4*)(h + (size_t)col[p] * FIN);
#pragma unroll
        for (int j = 0; j < FIN / 4; ++j) {
            float4 v = r[j];
            acc[4 * j + 0] += v.x;
            acc[4 * j + 1] += v.y;
            acc[4 * j + 2] += v.z;
            acc[4 * j + 3] += v.w;
        }
    }
    int deg = p1 - p0;
    float inv = 1.f / (float)(deg > 1 ? deg : 1);
#pragma unroll
    for (int k = 0; k < FIN; ++k) acc[k] *= inv;
    float* out = tmp + (size_t)i * FOUT;
#pragma unroll 1
    for (int o = 0; o < FOUT; ++o) {
        const float* w = WlT + o * FIN;
        float h0 = 0.f, h1 = 0.f, h2 = 0.f, h3 = 0.f;
#pragma unroll
        for (int k = 0; k < FIN; k += 4) {
            h0 = fmaf(acc[k + 0], w[k + 0], h0);
            h1 = fmaf(acc[k + 1], w[k + 1], h1);
            h2 = fmaf(acc[k + 2], w[k + 2], h2);
            h3 = fmaf(acc[k + 3], w[k + 3], h3);
        }
        out[o] = (h0 + h1) + (h2 + h3);
    }
}

// ---------------- SAGE: + lin_r(root) + bias (+relu) ----------------
template <int FIN, int FOUT, bool RELU>
__global__ __launch_bounds__(64, 2) void root_mm_kernel(
    const float* __restrict__ tmp, const float* __restrict__ hin,
    const float* __restrict__ WrT, const float* __restrict__ b,
    float* __restrict__ out, int n) {
    int i = blockIdx.x * 64 + threadIdx.x;
    if (i >= n) return;
    float hv[FIN];
    const float4* r = (const float4*)(hin + (size_t)i * FIN);
#pragma unroll
    for (int j = 0; j < FIN / 4; ++j) {
        float4 v = r[j];
        hv[4 * j + 0] = v.x;
        hv[4 * j + 1] = v.y;
        hv[4 * j + 2] = v.z;
        hv[4 * j + 3] = v.w;
    }
    const float* ti = tmp + (size_t)i * FOUT;
    float* oi = out + (size_t)i * FOUT;
#pragma unroll 1
    for (int o = 0; o < FOUT; ++o) {
        const float* w = WrT + o * FIN;
        float h0 = 0.f, h1 = 0.f, h2 = 0.f, h3 = 0.f;
#pragma unroll
        for (int k = 0; k < FIN; k += 4) {
            h0 = fmaf(hv[k + 0], w[k + 0], h0);
            h1 = fmaf(hv[k + 1], w[k + 1], h1);
            h2 = fmaf(hv[k + 2], w[k + 2], h2);
            h3 = fmaf(hv[k + 3], w[k + 3], h3);
        }
        float v = ti[o] + b[o] + (h0 + h1) + (h2 + h3);
        if (RELU) v = fmaxf(v, 0.f);
        oi[o] = v;
    }
}

// ---------------- edge MLP: relu(emb@Wf1+bf1)@Wf2+bf2 ----------------
// one thread per edge; emb (128 floats) in VGPRs; Wf1T via uniform scalar loads.
__global__ __launch_bounds__(64, 2) void edge_mlp_kernel(
    const float* __restrict__ ne, const int* __restrict__ src, const int* __restrict__ dst,
    const float* __restrict__ Wf1T, const float* __restrict__ bf1,
    const float* __restrict__ Wf2, const float* __restrict__ bf2,
    float* __restrict__ out, int n) {
    int e = blockIdx.x * 64 + threadIdx.x;
    if (e >= n) return;
    float emb[128];
    const float4* a = (const float4*)(ne + (size_t)src[e] * 64);
    const float4* bptr = (const float4*)(ne + (size_t)dst[e] * 64);
#pragma unroll
    for (int j = 0; j < 16; ++j) {
        float4 v = a[j];
        emb[4 * j + 0] = v.x; emb[4 * j + 1] = v.y; emb[4 * j + 2] = v.z; emb[4 * j + 3] = v.w;
    }
#pragma unroll
    for (int j = 0; j < 16; ++j) {
        float4 v = bptr[j];
        emb[64 + 4 * j + 0] = v.x; emb[64 + 4 * j + 1] = v.y;
        emb[64 + 4 * j + 2] = v.z; emb[64 + 4 * j + 3] = v.w;
    }
    float acc = 0.f;
#pragma unroll 1
    for (int o = 0; o < 128; ++o) {
        const float* w = Wf1T + o * 128;
        float h0 = 0.f, h1 = 0.f, h2 = 0.f, h3 = 0.f;
#pragma unroll
        for (int k = 0; k < 128; k += 4) {
            h0 = fmaf(emb[k + 0], w[k + 0], h0);
            h1 = fmaf(emb[k + 1], w[k + 1], h1);
            h2 = fmaf(emb[k + 2], w[k + 2], h2);
            h3 = fmaf(emb[k + 3], w[k + 3], h3);
        }
        float hval = bf1[o] + (h0 + h1) + (h2 + h3);
        hval = fmaxf(hval, 0.f);
        acc = fmaf(hval, Wf2[o], acc);
    }
    out[e] = acc + bf2[0];
}

// ---------------- classifier: ne @ Wc + bc ----------------
__global__ __launch_bounds__(64, 2) void classifier_kernel(
    const float* __restrict__ ne, const float* __restrict__ Wc,
    const float* __restrict__ bc, float* __restrict__ out, int n) {
    int i = blockIdx.x * 64 + threadIdx.x;
    if (i >= n) return;
    float v[64];
    const float4* r = (const float4*)(ne + (size_t)i * 64);
#pragma unroll
    for (int j = 0; j < 16; ++j) {
        float4 q = r[j];
        v[4 * j + 0] = q.x; v[4 * j + 1] = q.y; v[4 * j + 2] = q.z; v[4 * j + 3] = q.w;
    }
#pragma unroll
    for (int c = 0; c < 4; ++c) {
        float a0 = 0.f, a1 = 0.f, a2 = 0.f, a3 = 0.f;
#pragma unroll
        for (int k = 0; k < 64; k += 4) {
            a0 = fmaf(v[k + 0], Wc[(k + 0) * 4 + c], a0);
            a1 = fmaf(v[k + 1], Wc[(k + 1) * 4 + c], a1);
            a2 = fmaf(v[k + 2], Wc[(k + 2) * 4 + c], a2);
            a3 = fmaf(v[k + 3], Wc[(k + 3) * 4 + c], a3);
        }
        out[(size_t)i * 4 + c] = bc[c] + (a0 + a1) + (a2 + a3);
    }
}

extern "C" void kernel_launch(void* const* d_in, const int* in_sizes, int n_in,
                              void* d_out, int out_size, void* d_ws, size_t ws_size,
                              hipStream_t stream) {
    const float* x   = (const float*)d_in[0];
    const int*   ei  = (const int*)d_in[1];
    const int*   src = ei;
    const int*   dst = ei + NE;
    const float* Wl0 = (const float*)d_in[2];
    const float* Wr0 = (const float*)d_in[3];
    const float* b0  = (const float*)d_in[4];
    const float* Wl1 = (const float*)d_in[5];
    const float* Wr1 = (const float*)d_in[6];
    const float* b1  = (const float*)d_in[7];
    const float* Wl2 = (const float*)d_in[8];
    const float* Wr2 = (const float*)d_in[9];
    const float* b2  = (const float*)d_in[10];
    const float* Wf1 = (const float*)d_in[11];
    const float* bf1 = (const float*)d_in[12];
    const float* Wf2 = (const float*)d_in[13];
    const float* bf2 = (const float*)d_in[14];
    const float* Wc  = (const float*)d_in[15];
    const float* bc  = (const float*)d_in[16];

    float* ws = (float*)d_ws;
    float* WlT0 = ws; ws += 128 * 128;
    float* WrT0 = ws; ws += 128 * 128;
    float* WlT1 = ws; ws += 128 * 128;
    float* WrT1 = ws; ws += 128 * 128;
    float* WlT2 = ws; ws += 128 * 64;
    float* WrT2 = ws; ws += 128 * 64;
    float* Wf1T = ws; ws += 128 * 128;
    int* off    = (int*)ws; ws += 50004;   // NN+1, padded
    int* cursor = (int*)ws; ws += 50000;   // also used as deg
    int* col    = (int*)ws; ws += 800000;
    ws += 4;                               // realign to 16B
    float* h1  = ws; ws += (size_t)NN * 128;
    float* h2  = ws; ws += (size_t)NN * 128;
    float* tmp = ws; ws += (size_t)NN * 128;

    float* ne = (float*)d_out;               // [NN,64]
    float* cf = ne + (size_t)NN * 64;        // [NE,1]
    float* sc = cf + NE;                     // [NN,4]

    int* deg = cursor;

    // --- CSR build ---
    hipMemsetAsync(deg, 0, NN * sizeof(int), stream);
    count_deg_kernel<<<(NE + 255) / 256, 256, 0, stream>>>(dst, deg, NE);
    scan_kernel<<<1, 1024, 0, stream>>>(deg, off, NN);
    init_cursor_kernel<<<(NN + 255) / 256, 256, 0, stream>>>(off, cursor, NN);
    fill_kernel<<<(NE + 255) / 256, 256, 0, stream>>>(src, dst, cursor, col, NE);

    // --- weight transposes ---
    transpose_kernel<<<(128 * 128 + 255) / 256, 256, 0, stream>>>(Wl0, WlT0, 128, 128);
    transpose_kernel<<<(128 * 128 + 255) / 256, 256, 0, stream>>>(Wr0, WrT0, 128, 128);
    transpose_kernel<<<(128 * 128 + 255) / 256, 256, 0, stream>>>(Wl1, WlT1, 128, 128);
    transpose_kernel<<<(128 * 128 + 255) / 256, 256, 0, stream>>>(Wr1, WrT1, 128, 128);
    transpose_kernel<<<(128 * 64 + 255) / 256, 256, 0, stream>>>(Wl2, WlT2, 128, 64);
    transpose_kernel<<<(128 * 64 + 255) / 256, 256, 0, stream>>>(Wr2, WrT2, 128, 64);
    transpose_kernel<<<(128 * 128 + 255) / 256, 256, 0, stream>>>(Wf1, Wf1T, 128, 128);

    int ngrid = (NN + 63) / 64;
    int egrid = (NE + 63) / 64;

    // --- layer 0 ---
    agg_mean_mm_kernel<128, 128><<<ngrid, 64, 0, stream>>>(x, off, col, WlT0, tmp, NN);
    root_mm_kernel<128, 128, true><<<ngrid, 64, 0, stream>>>(tmp, x, WrT0, b0, h1, NN);
    // --- layer 1 ---
    agg_mean_mm_kernel<128, 128><<<ngrid, 64, 0, stream>>>(h1, off, col, WlT1, tmp, NN);
    root_mm_kernel<128, 128, true><<<ngrid, 64, 0, stream>>>(tmp, h1, WrT1, b1, h2, NN);
    // --- layer 2 (no relu), writes node embeddings directly to d_out ---
    agg_mean_mm_kernel<128, 64><<<ngrid, 64, 0, stream>>>(h2, off, col, WlT2, tmp, NN);
    root_mm_kernel<128, 64, false><<<ngrid, 64, 0, stream>>>(tmp, h2, WrT2, b2, ne, NN);

    // --- heads ---
    edge_mlp_kernel<<<egrid, 64, 0, stream>>>(ne, src, dst, Wf1T, bf1, Wf2, bf2, cf, NE);
    classifier_kernel<<<ngrid, 64, 0, stream>>>(ne, Wc, bc, sc, NN);
}

// Round 3
// 513.895 us; speedup vs baseline: 5.2352x; 5.2352x over previous
//
#include <hip/hip_runtime.h>

#define NN 50000
#define NE 800000

typedef __attribute__((ext_vector_type(8))) short bf16x8;
typedef __attribute__((ext_vector_type(4))) float f32x4;

__device__ inline short f2bf(float f) {
    union { float f; unsigned u; } v; v.f = f;
    unsigned r = v.u + 0x7fffu + ((v.u >> 16) & 1u);
    return (short)(r >> 16);
}
__device__ inline float bf2f(short s) {
    union { unsigned u; float f; } v;
    v.u = ((unsigned)(unsigned short)s) << 16;
    return v.f;
}

// ---------------- CSR build ----------------
__global__ __launch_bounds__(256) void count_deg_kernel(const int* __restrict__ dst,
                                                        int* __restrict__ deg, int n) {
    int e = blockIdx.x * 256 + threadIdx.x;
    if (e < n) atomicAdd(&deg[dst[e]], 1);
}

__global__ __launch_bounds__(1024) void scan_kernel(const int* __restrict__ deg,
                                                    int* __restrict__ off, int n) {
    __shared__ int s[1024];
    int t = threadIdx.x;
    int chunk = (n + 1023) >> 10;
    int lo = t * chunk; if (lo > n) lo = n;
    int hi = lo + chunk; if (hi > n) hi = n;
    int sum = 0;
    for (int i = lo; i < hi; ++i) sum += deg[i];
    s[t] = sum;
    __syncthreads();
    for (int d = 1; d < 1024; d <<= 1) {
        int v = (t >= d) ? s[t - d] : 0;
        __syncthreads();
        s[t] += v;
        __syncthreads();
    }
    int base = (t == 0) ? 0 : s[t - 1];
    for (int i = lo; i < hi; ++i) { off[i] = base; base += deg[i]; }
    if (t == 1023) off[n] = s[1023];
}

__global__ __launch_bounds__(256) void init_cursor_kernel(const int* __restrict__ off,
                                                          int* __restrict__ cursor, int n) {
    int i = blockIdx.x * 256 + threadIdx.x;
    if (i < n) cursor[i] = off[i];
}

__global__ __launch_bounds__(256) void fill_kernel(const int* __restrict__ src,
                                                   const int* __restrict__ dst,
                                                   int* __restrict__ cursor,
                                                   int* __restrict__ col, int n) {
    int e = blockIdx.x * 256 + threadIdx.x;
    if (e < n) {
        int p = atomicAdd(&cursor[dst[e]], 1);
        col[p] = src[e];
    }
}

// ---------------- pack B = [B0;B1] (f32 row-major, K x N) into bf16 MFMA fragments ----
// layout: for frag-step fs = ct*(K/32)+ks, lane l, elem j:
//   out[(fs*64+l)*8+j] = B[ks*32+(l>>4)*8+j][ct*16+(l&15)]
__global__ __launch_bounds__(256) void pack_b_kernel(
    const float* __restrict__ B0, const float* __restrict__ B1,
    int K0, int K, int N, short* __restrict__ out) {
    int t = blockIdx.x * 256 + threadIdx.x;
    int total = (N >> 4) * (K >> 5) * 64;
    if (t >= total) return;
    int l = t & 63;
    int fs = t >> 6;
    int KS = K >> 5;
    int ct = fs / KS, ks = fs - ct * KS;
    int coln = ct * 16 + (l & 15);
    int k0 = ks * 32 + (l >> 4) * 8;
    bf16x8 v;
#pragma unroll
    for (int j = 0; j < 8; ++j) {
        int k = k0 + j;
        float f = (k < K0) ? B0[(size_t)k * N + coln] : B1[(size_t)(k - K0) * N + coln];
        v[j] = f2bf(f);
    }
    *(bf16x8*)(out + (size_t)t * 8) = v;
}

// ---------------- mean aggregation: 16 lanes per node, 8 cols/lane, bf16 out ---------
template <bool IN_F32>
__global__ __launch_bounds__(256) void agg_mean_kernel(
    const void* __restrict__ hv, const int* __restrict__ off,
    const int* __restrict__ col, short* __restrict__ meanb, int n) {
    int t = blockIdx.x * 256 + threadIdx.x;
    int node = t >> 4, q = t & 15;
    if (node >= n) return;
    int p0 = off[node], p1 = off[node + 1];
    float a0 = 0.f, a1 = 0.f, a2 = 0.f, a3 = 0.f, a4 = 0.f, a5 = 0.f, a6 = 0.f, a7 = 0.f;
    for (int p = p0; p < p1; ++p) {
        int c = col[p];
        if (IN_F32) {
            const float* r = (const float*)hv + (size_t)c * 128 + q * 8;
            float4 v0 = *(const float4*)r;
            float4 v1 = *(const float4*)(r + 4);
            a0 += v0.x; a1 += v0.y; a2 += v0.z; a3 += v0.w;
            a4 += v1.x; a5 += v1.y; a6 += v1.z; a7 += v1.w;
        } else {
            bf16x8 v = *(const bf16x8*)((const short*)hv + (size_t)c * 128 + q * 8);
            a0 += bf2f(v[0]); a1 += bf2f(v[1]); a2 += bf2f(v[2]); a3 += bf2f(v[3]);
            a4 += bf2f(v[4]); a5 += bf2f(v[5]); a6 += bf2f(v[6]); a7 += bf2f(v[7]);
        }
    }
    int deg = p1 - p0;
    float inv = 1.0f / (float)(deg > 1 ? deg : 1);
    bf16x8 o;
    o[0] = f2bf(a0 * inv); o[1] = f2bf(a1 * inv); o[2] = f2bf(a2 * inv); o[3] = f2bf(a3 * inv);
    o[4] = f2bf(a4 * inv); o[5] = f2bf(a5 * inv); o[6] = f2bf(a6 * inv); o[7] = f2bf(a7 * inv);
    *(bf16x8*)(meanb + (size_t)node * 128 + q * 8) = o;
}

// ---------------- SAGE GEMM: out = relu?([mean|h] @ Wp + b), K=256 ----------------
// mean is bf16 [n,128]; root is f32 or bf16 [n,128]; out is bf16 or f32 [n, NT*16].
template <int NT, bool RELU, bool ROOT_F32, bool OUT_BF16>
__global__ __launch_bounds__(256) void sage_gemm_kernel(
    const short* __restrict__ meanb, const void* __restrict__ rootv,
    const short* __restrict__ Wp, const float* __restrict__ b,
    void* __restrict__ outv, int n) {
    int wave = (blockIdx.x * 256 + threadIdx.x) >> 6;
    int lane = threadIdx.x & 63;
    int rowbase = wave * 32;
    if (rowbase >= n) return;
    int g = lane >> 4, c = lane & 15;

    bf16x8 afrag[2][8];
#pragma unroll
    for (int s = 0; s < 2; ++s) {
        int i = rowbase + s * 16 + c;
        if (i >= n) i = n - 1;
        const short* mrow = meanb + (size_t)i * 128;
#pragma unroll
        for (int ks = 0; ks < 4; ++ks)
            afrag[s][ks] = *(const bf16x8*)(mrow + ks * 32 + g * 8);
        if (ROOT_F32) {
            const float* hr = (const float*)rootv + (size_t)i * 128;
#pragma unroll
            for (int ks = 4; ks < 8; ++ks) {
                const float* p = hr + (ks - 4) * 32 + g * 8;
                float4 v0 = *(const float4*)p;
                float4 v1 = *(const float4*)(p + 4);
                bf16x8 a;
                a[0] = f2bf(v0.x); a[1] = f2bf(v0.y); a[2] = f2bf(v0.z); a[3] = f2bf(v0.w);
                a[4] = f2bf(v1.x); a[5] = f2bf(v1.y); a[6] = f2bf(v1.z); a[7] = f2bf(v1.w);
                afrag[s][ks] = a;
            }
        } else {
            const short* hr = (const short*)rootv + (size_t)i * 128;
#pragma unroll
            for (int ks = 4; ks < 8; ++ks)
                afrag[s][ks] = *(const bf16x8*)(hr + (ks - 4) * 32 + g * 8);
        }
    }

    f32x4 acc[2][NT];
    f32x4 z = {0.f, 0.f, 0.f, 0.f};
#pragma unroll
    for (int s = 0; s < 2; ++s)
#pragma unroll
        for (int ct = 0; ct < NT; ++ct) acc[s][ct] = z;

#pragma unroll
    for (int ct = 0; ct < NT; ++ct)
#pragma unroll
        for (int ks = 0; ks < 8; ++ks) {
            bf16x8 bfv = *(const bf16x8*)(Wp + ((size_t)(ct * 8 + ks) * 64 + lane) * 8);
            acc[0][ct] = __builtin_amdgcn_mfma_f32_16x16x32_bf16(afrag[0][ks], bfv, acc[0][ct], 0, 0, 0);
            acc[1][ct] = __builtin_amdgcn_mfma_f32_16x16x32_bf16(afrag[1][ks], bfv, acc[1][ct], 0, 0, 0);
        }

    const int N = NT * 16;
#pragma unroll
    for (int s = 0; s < 2; ++s)
#pragma unroll
        for (int ct = 0; ct < NT; ++ct)
#pragma unroll
            for (int r = 0; r < 4; ++r) {
                int row = rowbase + s * 16 + g * 4 + r;
                if (row < n) {
                    float v = acc[s][ct][r] + b[ct * 16 + c];
                    if (RELU) v = fmaxf(v, 0.f);
                    if (OUT_BF16)
                        ((short*)outv)[(size_t)row * N + ct * 16 + c] = f2bf(v);
                    else
                        ((float*)outv)[(size_t)row * N + ct * 16 + c] = v;
                }
            }
}

// ---------------- edge MLP: relu([ne[src]|ne[dst]] @ Wfp + bf1) . Wf2 + bf2 ----------
__global__ __launch_bounds__(256) void edge_mlp_mfma_kernel(
    const float* __restrict__ ne, const int* __restrict__ src, const int* __restrict__ dst,
    const short* __restrict__ Wp, const float* __restrict__ bf1,
    const float* __restrict__ Wf2, const float* __restrict__ bf2,
    float* __restrict__ out, int nE) {
    int wave = (blockIdx.x * 256 + threadIdx.x) >> 6;
    int lane = threadIdx.x & 63;
    int rowbase = wave * 32;
    if (rowbase >= nE) return;
    int g = lane >> 4, c = lane & 15;

    bf16x8 afrag[2][4];
#pragma unroll
    for (int s = 0; s < 2; ++s) {
        int e = rowbase + s * 16 + c;
        int ns = src[e], nd = dst[e];
        const float* rs = ne + (size_t)ns * 64;
        const float* rd = ne + (size_t)nd * 64;
#pragma unroll
        for (int ks = 0; ks < 4; ++ks) {
            const float* p = (ks < 2) ? (rs + ks * 32) : (rd + (ks - 2) * 32);
            float4 v0 = *(const float4*)(p + g * 8);
            float4 v1 = *(const float4*)(p + g * 8 + 4);
            bf16x8 a;
            a[0] = f2bf(v0.x); a[1] = f2bf(v0.y); a[2] = f2bf(v0.z); a[3] = f2bf(v0.w);
            a[4] = f2bf(v1.x); a[5] = f2bf(v1.y); a[6] = f2bf(v1.z); a[7] = f2bf(v1.w);
            afrag[s][ks] = a;
        }
    }

    f32x4 acc[2][8];
    f32x4 z = {0.f, 0.f, 0.f, 0.f};
#pragma unroll
    for (int s = 0; s < 2; ++s)
#pragma unroll
        for (int ct = 0; ct < 8; ++ct) acc[s][ct] = z;

#pragma unroll
    for (int ct = 0; ct < 8; ++ct)
#pragma unroll
        for (int ks = 0; ks < 4; ++ks) {
            bf16x8 bfv = *(const bf16x8*)(Wp + ((size_t)(ct * 4 + ks) * 64 + lane) * 8);
            acc[0][ct] = __builtin_amdgcn_mfma_f32_16x16x32_bf16(afrag[0][ks], bfv, acc[0][ct], 0, 0, 0);
            acc[1][ct] = __builtin_amdgcn_mfma_f32_16x16x32_bf16(afrag[1][ks], bfv, acc[1][ct], 0, 0, 0);
        }

    float bf1v[8], wf2v[8];
#pragma unroll
    for (int ct = 0; ct < 8; ++ct) {
        bf1v[ct] = bf1[ct * 16 + c];
        wf2v[ct] = Wf2[ct * 16 + c];
    }
    float bias2 = bf2[0];
#pragma unroll
    for (int s = 0; s < 2; ++s)
#pragma unroll
        for (int r = 0; r < 4; ++r) {
            float part = 0.f;
#pragma unroll
            for (int ct = 0; ct < 8; ++ct) {
                float hv = acc[s][ct][r] + bf1v[ct];
                hv = fmaxf(hv, 0.f);
                part = fmaf(hv, wf2v[ct], part);
            }
#pragma unroll
            for (int o = 1; o < 16; o <<= 1)
                part += __shfl_xor(part, o);
            if (c == 0) {
                int row = rowbase + s * 16 + g * 4 + r;
                out[row] = part + bias2;
            }
        }
}

// ---------------- classifier: ne @ Wc + bc ----------------
__global__ __launch_bounds__(64, 2) void classifier_kernel(
    const float* __restrict__ ne, const float* __restrict__ Wc,
    const float* __restrict__ bc, float* __restrict__ out, int n) {
    int i = blockIdx.x * 64 + threadIdx.x;
    if (i >= n) return;
    float v[64];
    const float4* r = (const float4*)(ne + (size_t)i * 64);
#pragma unroll
    for (int j = 0; j < 16; ++j) {
        float4 q = r[j];
        v[4 * j + 0] = q.x; v[4 * j + 1] = q.y; v[4 * j + 2] = q.z; v[4 * j + 3] = q.w;
    }
#pragma unroll
    for (int cidx = 0; cidx < 4; ++cidx) {
        float a0 = 0.f, a1 = 0.f, a2 = 0.f, a3 = 0.f;
#pragma unroll
        for (int k = 0; k < 64; k += 4) {
            a0 = fmaf(v[k + 0], Wc[(k + 0) * 4 + cidx], a0);
            a1 = fmaf(v[k + 1], Wc[(k + 1) * 4 + cidx], a1);
            a2 = fmaf(v[k + 2], Wc[(k + 2) * 4 + cidx], a2);
            a3 = fmaf(v[k + 3], Wc[(k + 3) * 4 + cidx], a3);
        }
        out[(size_t)i * 4 + cidx] = bc[cidx] + (a0 + a1) + (a2 + a3);
    }
}

extern "C" void kernel_launch(void* const* d_in, const int* in_sizes, int n_in,
                              void* d_out, int out_size, void* d_ws, size_t ws_size,
                              hipStream_t stream) {
    const float* x   = (const float*)d_in[0];
    const int*   ei  = (const int*)d_in[1];
    const int*   src = ei;
    const int*   dst = ei + NE;
    const float* Wl0 = (const float*)d_in[2];
    const float* Wr0 = (const float*)d_in[3];
    const float* b0  = (const float*)d_in[4];
    const float* Wl1 = (const float*)d_in[5];
    const float* Wr1 = (const float*)d_in[6];
    const float* b1  = (const float*)d_in[7];
    const float* Wl2 = (const float*)d_in[8];
    const float* Wr2 = (const float*)d_in[9];
    const float* b2  = (const float*)d_in[10];
    const float* Wf1 = (const float*)d_in[11];
    const float* bf1 = (const float*)d_in[12];
    const float* Wf2 = (const float*)d_in[13];
    const float* bf2 = (const float*)d_in[14];
    const float* Wc  = (const float*)d_in[15];
    const float* bc  = (const float*)d_in[16];

    // ---- workspace carve-up (total ~28.0 MiB) ----
    short* sp = (short*)d_ws;
    short* W0p = sp; sp += 256 * 128;            // 64 KiB
    short* W1p = sp; sp += 256 * 128;            // 64 KiB
    short* W2p = sp; sp += 256 * 64;             // 32 KiB
    short* Wfp = sp; sp += 128 * 128;            // 32 KiB
    short* meanb = sp; sp += (size_t)NN * 128;   // 12.8 MB, bf16 mean rows
    short* hb    = sp; sp += (size_t)NN * 128;   // 12.8 MB, bf16 h1/h2 (aliased)
    int* ip = (int*)sp;
    int* off    = ip; ip += 50008;               // NN+1 padded
    int* cursor = ip; ip += 50000;               // also deg
    int* col    = ip; ip += 800000;

    float* ne = (float*)d_out;               // [NN,64]
    float* cf = ne + (size_t)NN * 64;        // [NE]
    float* sc = cf + NE;                     // [NN,4]

    int* deg = cursor;

    // --- CSR build ---
    hipMemsetAsync(deg, 0, NN * sizeof(int), stream);
    count_deg_kernel<<<(NE + 255) / 256, 256, 0, stream>>>(dst, deg, NE);
    scan_kernel<<<1, 1024, 0, stream>>>(deg, off, NN);
    init_cursor_kernel<<<(NN + 255) / 256, 256, 0, stream>>>(off, cursor, NN);
    fill_kernel<<<(NE + 255) / 256, 256, 0, stream>>>(src, dst, cursor, col, NE);

    // --- pack weights into MFMA B-fragment order (bf16) ---
    pack_b_kernel<<<(4096 + 255) / 256, 256, 0, stream>>>(Wl0, Wr0, 128, 256, 128, W0p);
    pack_b_kernel<<<(4096 + 255) / 256, 256, 0, stream>>>(Wl1, Wr1, 128, 256, 128, W1p);
    pack_b_kernel<<<(2048 + 255) / 256, 256, 0, stream>>>(Wl2, Wr2, 128, 256, 64, W2p);
    pack_b_kernel<<<(2048 + 255) / 256, 256, 0, stream>>>(Wf1, Wf1, 128, 128, 128, Wfp);

    int agrid = (NN * 16 + 255) / 256;          // 3125
    int sgrid = ((NN + 31) / 32 + 3) / 4;       // 391 blocks x 4 waves
    int egrid = (NE / 32) / 4;                  // 6250

    // --- layer 0 (root = f32 x) ---
    agg_mean_kernel<true><<<agrid, 256, 0, stream>>>(x, off, col, meanb, NN);
    sage_gemm_kernel<8, true, true, true><<<sgrid, 256, 0, stream>>>(meanb, x, W0p, b0, hb, NN);
    // --- layer 1 (hb -> hb, per-wave-tile self-contained so aliasing is safe) ---
    agg_mean_kernel<false><<<agrid, 256, 0, stream>>>(hb, off, col, meanb, NN);
    sage_gemm_kernel<8, true, false, true><<<sgrid, 256, 0, stream>>>(meanb, hb, W1p, b1, hb, NN);
    // --- layer 2 -> node embeddings f32 (no relu) ---
    agg_mean_kernel<false><<<agrid, 256, 0, stream>>>(hb, off, col, meanb, NN);
    sage_gemm_kernel<4, false, false, false><<<sgrid, 256, 0, stream>>>(meanb, hb, W2p, b2, ne, NN);

    // --- heads ---
    edge_mlp_mfma_kernel<<<egrid, 256, 0, stream>>>(ne, src, dst, Wfp, bf1, Wf2, bf2, cf, NE);
    classifier_kernel<<<(NN + 63) / 64, 64, 0, stream>>>(ne, Wc, bc, sc, NN);
}

// Round 4
// 357.019 us; speedup vs baseline: 7.5356x; 1.4394x over previous
//
#include <hip/hip_runtime.h>

#define NN 50000
#define NE 800000

typedef __attribute__((ext_vector_type(8))) short bf16x8;
typedef __attribute__((ext_vector_type(4))) float f32x4;

__device__ inline short f2bf(float f) {
    union { float f; unsigned u; } v; v.f = f;
    unsigned r = v.u + 0x7fffu + ((v.u >> 16) & 1u);
    return (short)(r >> 16);
}
__device__ inline float bf2f(short s) {
    union { unsigned u; float f; } v;
    v.u = ((unsigned)(unsigned short)s) << 16;
    return v.f;
}

// ---------------- CSR build ----------------
__global__ __launch_bounds__(256) void count_deg_kernel(const int* __restrict__ dst,
                                                        int* __restrict__ deg, int n) {
    int e = blockIdx.x * 256 + threadIdx.x;
    if (e < n) atomicAdd(&deg[dst[e]], 1);
}

// block-local exclusive scan; bsum[b] = block total
__global__ __launch_bounds__(256) void scan1_kernel(const int* __restrict__ deg,
                                                    int* __restrict__ off,
                                                    int* __restrict__ bsum, int n) {
    __shared__ int s[256];
    int t = threadIdx.x;
    int i = blockIdx.x * 256 + t;
    int v = (i < n) ? deg[i] : 0;
    s[t] = v;
    __syncthreads();
    for (int d = 1; d < 256; d <<= 1) {
        int u = (t >= d) ? s[t - d] : 0;
        __syncthreads();
        s[t] += u;
        __syncthreads();
    }
    if (i < n) off[i] = s[t] - v;
    if (t == 255) bsum[blockIdx.x] = s[255];
}

__global__ __launch_bounds__(256) void scan2_kernel(int* __restrict__ bsum, int nb) {
    __shared__ int s[256];
    int t = threadIdx.x;
    int v = (t < nb) ? bsum[t] : 0;
    s[t] = v;
    __syncthreads();
    for (int d = 1; d < 256; d <<= 1) {
        int u = (t >= d) ? s[t - d] : 0;
        __syncthreads();
        s[t] += u;
        __syncthreads();
    }
    if (t < nb) bsum[t] = s[t] - v;   // exclusive block base
}

__global__ __launch_bounds__(256) void scan3_kernel(int* __restrict__ off,
                                                    const int* __restrict__ bsum,
                                                    int* __restrict__ cursor, int n, int total) {
    int i = blockIdx.x * 256 + threadIdx.x;
    if (i < n) {
        int v = off[i] + bsum[i >> 8];
        off[i] = v;
        cursor[i] = v;
    }
    if (i == 0) off[n] = total;
}

__global__ __launch_bounds__(256) void fill_kernel(const int* __restrict__ src,
                                                   const int* __restrict__ dst,
                                                   int* __restrict__ cursor,
                                                   int* __restrict__ col, int n) {
    int e = blockIdx.x * 256 + threadIdx.x;
    if (e < n) {
        int p = atomicAdd(&cursor[dst[e]], 1);
        col[p] = src[e];
    }
}

// ---------------- f32 -> bf16 convert (8 elems/thread) ----------------
__global__ __launch_bounds__(256) void cvt_bf16_kernel(const float* __restrict__ in,
                                                       short* __restrict__ outb, int n8) {
    int t = blockIdx.x * 256 + threadIdx.x;
    if (t >= n8) return;
    const float4* p = (const float4*)(in + (size_t)t * 8);
    float4 v0 = p[0], v1 = p[1];
    bf16x8 o;
    o[0] = f2bf(v0.x); o[1] = f2bf(v0.y); o[2] = f2bf(v0.z); o[3] = f2bf(v0.w);
    o[4] = f2bf(v1.x); o[5] = f2bf(v1.y); o[6] = f2bf(v1.z); o[7] = f2bf(v1.w);
    *(bf16x8*)(outb + (size_t)t * 8) = o;
}

// ---------------- pack B = [B0;B1] (f32 row-major, K x N) into bf16 MFMA fragments ----
__global__ __launch_bounds__(256) void pack_b_kernel(
    const float* __restrict__ B0, const float* __restrict__ B1,
    int K0, int K, int N, short* __restrict__ out) {
    int t = blockIdx.x * 256 + threadIdx.x;
    int total = (N >> 4) * (K >> 5) * 64;
    if (t >= total) return;
    int l = t & 63;
    int fs = t >> 6;
    int KS = K >> 5;
    int ct = fs / KS, ks = fs - ct * KS;
    int coln = ct * 16 + (l & 15);
    int k0 = ks * 32 + (l >> 4) * 8;
    bf16x8 v;
#pragma unroll
    for (int j = 0; j < 8; ++j) {
        int k = k0 + j;
        float f = (k < K0) ? B0[(size_t)k * N + coln] : B1[(size_t)(k - K0) * N + coln];
        v[j] = f2bf(f);
    }
    *(bf16x8*)(out + (size_t)t * 8) = v;
}

// ---------------- mean aggregation: 8 lanes/node, 16 cols/lane, bf16 in/out -------
__global__ __launch_bounds__(256) void agg_mean_kernel(
    const short* __restrict__ hbase, const int* __restrict__ off,
    const int* __restrict__ col, short* __restrict__ meanb, int n) {
    int t = blockIdx.x * 256 + threadIdx.x;
    int node = t >> 3, q = t & 7;
    if (node >= n) return;
    int p0 = off[node], p1 = off[node + 1];
    float a[16];
#pragma unroll
    for (int k = 0; k < 16; ++k) a[k] = 0.f;
    int qo = q * 16;
    int p = p0;
    for (; p + 1 < p1; p += 2) {
        const short* r0 = hbase + (size_t)col[p] * 128 + qo;
        const short* r1 = hbase + (size_t)col[p + 1] * 128 + qo;
        bf16x8 u0 = *(const bf16x8*)r0;
        bf16x8 u1 = *(const bf16x8*)(r0 + 8);
        bf16x8 w0 = *(const bf16x8*)r1;
        bf16x8 w1 = *(const bf16x8*)(r1 + 8);
#pragma unroll
        for (int k = 0; k < 8; ++k) {
            a[k]     += bf2f(u0[k]) + bf2f(w0[k]);
            a[k + 8] += bf2f(u1[k]) + bf2f(w1[k]);
        }
    }
    if (p < p1) {
        const short* r0 = hbase + (size_t)col[p] * 128 + qo;
        bf16x8 u0 = *(const bf16x8*)r0;
        bf16x8 u1 = *(const bf16x8*)(r0 + 8);
#pragma unroll
        for (int k = 0; k < 8; ++k) {
            a[k]     += bf2f(u0[k]);
            a[k + 8] += bf2f(u1[k]);
        }
    }
    int deg = p1 - p0;
    float inv = 1.f / (float)(deg > 1 ? deg : 1);
    bf16x8 o0, o1;
#pragma unroll
    for (int k = 0; k < 8; ++k) {
        o0[k] = f2bf(a[k] * inv);
        o1[k] = f2bf(a[k + 8] * inv);
    }
    *(bf16x8*)(meanb + (size_t)node * 128 + qo) = o0;
    *(bf16x8*)(meanb + (size_t)node * 128 + qo + 8) = o1;
}

// ---------------- SAGE GEMM: out = relu?([mean|root] @ Wp + b), K=256, A all-bf16 ---
// MODE 0: write bf16 to (short*)outv [n, NT*16]
// MODE 1: write f32 to (float*)outv [n, 64] AND bf16 copy to neb (stride 128 shorts)
// NOTE: meanb/root/outv/neb may alias (in-place layer GEMMs; neb into meanb slots) —
// per-row reads complete before same-wave epilogue stores; rows are wave-private.
template <int NT, bool RELU, int MODE>
__global__ __launch_bounds__(256) void sage_gemm_kernel(
    const short* meanb, const short* root,
    const short* __restrict__ Wp, const float* __restrict__ b,
    void* outv, short* neb, int n) {
    int wave = (blockIdx.x * 256 + threadIdx.x) >> 6;
    int lane = threadIdx.x & 63;
    int rowbase = wave * 32;
    if (rowbase >= n) return;
    int g = lane >> 4, c = lane & 15;

    bf16x8 afrag[2][8];
#pragma unroll
    for (int s = 0; s < 2; ++s) {
        int i = rowbase + s * 16 + c;
        if (i >= n) i = n - 1;
        const short* mrow = meanb + (size_t)i * 128;
        const short* hrow = root + (size_t)i * 128;
#pragma unroll
        for (int ks = 0; ks < 4; ++ks) {
            afrag[s][ks]     = *(const bf16x8*)(mrow + ks * 32 + g * 8);
            afrag[s][ks + 4] = *(const bf16x8*)(hrow + ks * 32 + g * 8);
        }
    }

    f32x4 acc[2][NT];
    f32x4 z = {0.f, 0.f, 0.f, 0.f};
#pragma unroll
    for (int s = 0; s < 2; ++s)
#pragma unroll
        for (int ct = 0; ct < NT; ++ct) acc[s][ct] = z;

#pragma unroll
    for (int ct = 0; ct < NT; ++ct)
#pragma unroll
        for (int ks = 0; ks < 8; ++ks) {
            bf16x8 bfv = *(const bf16x8*)(Wp + ((size_t)(ct * 8 + ks) * 64 + lane) * 8);
            acc[0][ct] = __builtin_amdgcn_mfma_f32_16x16x32_bf16(afrag[0][ks], bfv, acc[0][ct], 0, 0, 0);
            acc[1][ct] = __builtin_amdgcn_mfma_f32_16x16x32_bf16(afrag[1][ks], bfv, acc[1][ct], 0, 0, 0);
        }

    const int N = NT * 16;
#pragma unroll
    for (int s = 0; s < 2; ++s)
#pragma unroll
        for (int ct = 0; ct < NT; ++ct)
#pragma unroll
            for (int r = 0; r < 4; ++r) {
                int row = rowbase + s * 16 + g * 4 + r;
                if (row < n) {
                    float v = acc[s][ct][r] + b[ct * 16 + c];
                    if (RELU) v = fmaxf(v, 0.f);
                    if (MODE == 0) {
                        ((short*)outv)[(size_t)row * N + ct * 16 + c] = f2bf(v);
                    } else {
                        ((float*)outv)[(size_t)row * N + ct * 16 + c] = v;
                        neb[(size_t)row * 128 + ct * 16 + c] = f2bf(v);
                    }
                }
            }
}

// ---------------- edge MLP: relu([neb[src]|neb[dst]] @ Wfp + bf1) . Wf2 + bf2 -------
// neb rows: 64 bf16 of data at stride 128 shorts (aliased into meanb slots)
__global__ __launch_bounds__(256) void edge_mlp_mfma_kernel(
    const short* __restrict__ neb, const int* __restrict__ src, const int* __restrict__ dst,
    const short* __restrict__ Wp, const float* __restrict__ bf1,
    const float* __restrict__ Wf2, const float* __restrict__ bf2,
    float* __restrict__ out, int nE) {
    int wave = (blockIdx.x * 256 + threadIdx.x) >> 6;
    int lane = threadIdx.x & 63;
    int rowbase = wave * 32;
    if (rowbase >= nE) return;
    int g = lane >> 4, c = lane & 15;

    bf16x8 afrag[2][4];
#pragma unroll
    for (int s = 0; s < 2; ++s) {
        int e = rowbase + s * 16 + c;
        const short* rs = neb + (size_t)src[e] * 128;
        const short* rd = neb + (size_t)dst[e] * 128;
        afrag[s][0] = *(const bf16x8*)(rs + g * 8);
        afrag[s][1] = *(const bf16x8*)(rs + 32 + g * 8);
        afrag[s][2] = *(const bf16x8*)(rd + g * 8);
        afrag[s][3] = *(const bf16x8*)(rd + 32 + g * 8);
    }

    f32x4 acc[2][8];
    f32x4 z = {0.f, 0.f, 0.f, 0.f};
#pragma unroll
    for (int s = 0; s < 2; ++s)
#pragma unroll
        for (int ct = 0; ct < 8; ++ct) acc[s][ct] = z;

#pragma unroll
    for (int ct = 0; ct < 8; ++ct)
#pragma unroll
        for (int ks = 0; ks < 4; ++ks) {
            bf16x8 bfv = *(const bf16x8*)(Wp + ((size_t)(ct * 4 + ks) * 64 + lane) * 8);
            acc[0][ct] = __builtin_amdgcn_mfma_f32_16x16x32_bf16(afrag[0][ks], bfv, acc[0][ct], 0, 0, 0);
            acc[1][ct] = __builtin_amdgcn_mfma_f32_16x16x32_bf16(afrag[1][ks], bfv, acc[1][ct], 0, 0, 0);
        }

    float bf1v[8], wf2v[8];
#pragma unroll
    for (int ct = 0; ct < 8; ++ct) {
        bf1v[ct] = bf1[ct * 16 + c];
        wf2v[ct] = Wf2[ct * 16 + c];
    }
    float bias2 = bf2[0];
#pragma unroll
    for (int s = 0; s < 2; ++s)
#pragma unroll
        for (int r = 0; r < 4; ++r) {
            float part = 0.f;
#pragma unroll
            for (int ct = 0; ct < 8; ++ct) {
                float hv = acc[s][ct][r] + bf1v[ct];
                hv = fmaxf(hv, 0.f);
                part = fmaf(hv, wf2v[ct], part);
            }
#pragma unroll
            for (int o = 1; o < 16; o <<= 1)
                part += __shfl_xor(part, o);
            if (c == 0) {
                int row = rowbase + s * 16 + g * 4 + r;
                out[row] = part + bias2;
            }
        }
}

// ---------------- classifier: ne @ Wc + bc ----------------
__global__ __launch_bounds__(64, 2) void classifier_kernel(
    const float* __restrict__ ne, const float* __restrict__ Wc,
    const float* __restrict__ bc, float* __restrict__ out, int n) {
    int i = blockIdx.x * 64 + threadIdx.x;
    if (i >= n) return;
    float v[64];
    const float4* r = (const float4*)(ne + (size_t)i * 64);
#pragma unroll
    for (int j = 0; j < 16; ++j) {
        float4 q = r[j];
        v[4 * j + 0] = q.x; v[4 * j + 1] = q.y; v[4 * j + 2] = q.z; v[4 * j + 3] = q.w;
    }
#pragma unroll
    for (int cidx = 0; cidx < 4; ++cidx) {
        float a0 = 0.f, a1 = 0.f, a2 = 0.f, a3 = 0.f;
#pragma unroll
        for (int k = 0; k < 64; k += 4) {
            a0 = fmaf(v[k + 0], Wc[(k + 0) * 4 + cidx], a0);
            a1 = fmaf(v[k + 1], Wc[(k + 1) * 4 + cidx], a1);
            a2 = fmaf(v[k + 2], Wc[(k + 2) * 4 + cidx], a2);
            a3 = fmaf(v[k + 3], Wc[(k + 3) * 4 + cidx], a3);
        }
        out[(size_t)i * 4 + cidx] = bc[cidx] + (a0 + a1) + (a2 + a3);
    }
}

extern "C" void kernel_launch(void* const* d_in, const int* in_sizes, int n_in,
                              void* d_out, int out_size, void* d_ws, size_t ws_size,
                              hipStream_t stream) {
    const float* x   = (const float*)d_in[0];
    const int*   ei  = (const int*)d_in[1];
    const int*   src = ei;
    const int*   dst = ei + NE;
    const float* Wl0 = (const float*)d_in[2];
    const float* Wr0 = (const float*)d_in[3];
    const float* b0  = (const float*)d_in[4];
    const float* Wl1 = (const float*)d_in[5];
    const float* Wr1 = (const float*)d_in[6];
    const float* b1  = (const float*)d_in[7];
    const float* Wl2 = (const float*)d_in[8];
    const float* Wr2 = (const float*)d_in[9];
    const float* b2  = (const float*)d_in[10];
    const float* Wf1 = (const float*)d_in[11];
    const float* bf1 = (const float*)d_in[12];
    const float* Wf2 = (const float*)d_in[13];
    const float* bf2 = (const float*)d_in[14];
    const float* Wc  = (const float*)d_in[15];
    const float* bc  = (const float*)d_in[16];

    // ---- workspace carve-up (~29.4 MiB, same footprint as proven-safe R3) ----
    short* sp = (short*)d_ws;
    short* W0p = sp; sp += 256 * 128;
    short* W1p = sp; sp += 256 * 128;
    short* W2p = sp; sp += 256 * 64;
    short* Wfp = sp; sp += 128 * 128;
    short* meanb = sp; sp += (size_t)NN * 128;   // mean rows; layer2 also packs neb here
    short* hb    = sp; sp += (size_t)NN * 128;   // xb -> h1 -> h2 (aliased, in-place)
    int* ip = (int*)sp;
    int* off    = ip; ip += 50008;
    int* cursor = ip; ip += 50000;               // also deg
    int* col    = ip; ip += 800000;
    int* bsum   = ip; ip += 256;

    float* ne = (float*)d_out;               // [NN,64]
    float* cf = ne + (size_t)NN * 64;        // [NE]
    float* sc = cf + NE;                     // [NN,4]

    int* deg = cursor;
    const int NB = (NN + 255) / 256;         // 196

    // --- CSR build ---
    hipMemsetAsync(deg, 0, NN * sizeof(int), stream);
    count_deg_kernel<<<(NE + 255) / 256, 256, 0, stream>>>(dst, deg, NE);
    scan1_kernel<<<NB, 256, 0, stream>>>(deg, off, bsum, NN);
    scan2_kernel<<<1, 256, 0, stream>>>(bsum, NB);
    scan3_kernel<<<NB, 256, 0, stream>>>(off, bsum, cursor, NN, NE);
    fill_kernel<<<(NE + 255) / 256, 256, 0, stream>>>(src, dst, cursor, col, NE);

    // --- x -> bf16 (into hb region), weight packs ---
    cvt_bf16_kernel<<<(NN * 16 + 255) / 256, 256, 0, stream>>>(x, hb, NN * 16);
    pack_b_kernel<<<(4096 + 255) / 256, 256, 0, stream>>>(Wl0, Wr0, 128, 256, 128, W0p);
    pack_b_kernel<<<(4096 + 255) / 256, 256, 0, stream>>>(Wl1, Wr1, 128, 256, 128, W1p);
    pack_b_kernel<<<(2048 + 255) / 256, 256, 0, stream>>>(Wl2, Wr2, 128, 256, 64, W2p);
    pack_b_kernel<<<(2048 + 255) / 256, 256, 0, stream>>>(Wf1, Wf1, 128, 128, 128, Wfp);

    int agrid = (NN * 8 + 255) / 256;           // 1563
    int sgrid = ((NN + 31) / 32 + 3) / 4;       // 391
    int egrid = (NE / 32) / 4;                  // 6250

    // --- layer 0 (xb in hb; GEMM in-place hb -> h1) ---
    agg_mean_kernel<<<agrid, 256, 0, stream>>>(hb, off, col, meanb, NN);
    sage_gemm_kernel<8, true, 0><<<sgrid, 256, 0, stream>>>(meanb, hb, W0p, b0, hb, nullptr, NN);
    // --- layer 1 (in-place hb) ---
    agg_mean_kernel<<<agrid, 256, 0, stream>>>(hb, off, col, meanb, NN);
    sage_gemm_kernel<8, true, 0><<<sgrid, 256, 0, stream>>>(meanb, hb, W1p, b1, hb, nullptr, NN);
    // --- layer 2 -> ne (f32, d_out) + neb (bf16, into meanb slots) ---
    agg_mean_kernel<<<agrid, 256, 0, stream>>>(hb, off, col, meanb, NN);
    sage_gemm_kernel<4, false, 1><<<sgrid, 256, 0, stream>>>(meanb, hb, W2p, b2, ne, meanb, NN);

    // --- heads ---
    edge_mlp_mfma_kernel<<<egrid, 256, 0, stream>>>(meanb, src, dst, Wfp, bf1, Wf2, bf2, cf, NE);
    classifier_kernel<<<(NN + 63) / 64, 64, 0, stream>>>(ne, Wc, bc, sc, NN);
}